// Round 8
// baseline (789.339 us; speedup 1.0000x reference)
//
#include <hip/hip_runtime.h>
#include <hip/hip_bf16.h>

#define E_DIM 1024
#define NHEAD 16
#define DHEAD 64
#define FDIM 4096
#define LQ 512
#define LKV 2048
#define NB 4

typedef __bf16 bfx8 __attribute__((ext_vector_type(8)));
typedef float f32x4 __attribute__((ext_vector_type(4)));
typedef unsigned short us8 __attribute__((ext_vector_type(8)));
typedef unsigned short us4 __attribute__((ext_vector_type(4)));

__device__ __forceinline__ unsigned short f2bf(float f){
  union { float f; unsigned int u; } v; v.f = f;
  unsigned int u = v.u;
  u += 0x7FFFu + ((u >> 16) & 1u);   // RNE
  return (unsigned short)(u >> 16);
}

__device__ __forceinline__ float fexp2(float x){
#if __has_builtin(__builtin_amdgcn_exp2f)
  return __builtin_amdgcn_exp2f(x);
#else
  return exp2f(x);
#endif
}

// ---------------- fp32 -> bf16 convert (8 elems/thread, exact grid) ----------------
__global__ __launch_bounds__(256) void cvt_kernel(const float* __restrict__ src,
                                                  unsigned short* __restrict__ dst){
  size_t i = ((size_t)blockIdx.x * 256 + threadIdx.x) * 8;
  float4 a = *reinterpret_cast<const float4*>(src + i);
  float4 b = *reinterpret_cast<const float4*>(src + i + 4);
  us8 o;
  o[0]=f2bf(a.x); o[1]=f2bf(a.y); o[2]=f2bf(a.z); o[3]=f2bf(a.w);
  o[4]=f2bf(b.x); o[5]=f2bf(b.y); o[6]=f2bf(b.z); o[7]=f2bf(b.w);
  *reinterpret_cast<us8*>(dst + i) = o;
}

// ---------------- m97-structure GEMM: 128xBN tile, BK=64, global_load_lds(16B) -----
template<int BN, bool HASBIAS, bool RELU, bool OUTF, bool OUTB>
__global__ __launch_bounds__(256) void gemm128(
    const unsigned short* __restrict__ A, const unsigned short* __restrict__ W,
    const float* __restrict__ bias, float* __restrict__ Cf, unsigned short* __restrict__ Cb,
    int M, int N, int K, int lda, int ldw, int ldc)
{
  constexpr int BM  = 128;
  constexpr int NFB = BN / 32;
  __shared__ unsigned short As[BM * 64];
  __shared__ unsigned short Bs[BN * 64];

  const int tid = threadIdx.x, lane = tid & 63, w = tid >> 6;
  const int wr = w >> 1, wc = w & 1;
  const int m0 = blockIdx.y * BM, n0 = blockIdx.x * BN;
  const int l15 = lane & 15, l4 = lane >> 4;

  f32x4 acc[4][NFB] = {};

  for (int k0 = 0; k0 < K; k0 += 64){
    __syncthreads();
    #pragma unroll
    for (int c = 0; c < BM/32; c++){
      const int o = (c*256 + tid) * 16;
      const int row = o >> 7, colb = o & 127;
      __builtin_amdgcn_global_load_lds(
        (const __attribute__((address_space(1))) void*)
            ((const char*)A + ((long)(m0+row)*lda + k0)*2 + colb),
        (__attribute__((address_space(3))) unsigned int*)((char*)As + o), 16, 0, 0);
    }
    #pragma unroll
    for (int c = 0; c < BN/32; c++){
      const int o = (c*256 + tid) * 16;
      const int row = o >> 7, colb = o & 127;
      __builtin_amdgcn_global_load_lds(
        (const __attribute__((address_space(1))) void*)
            ((const char*)W + ((long)(n0+row)*ldw + k0)*2 + colb),
        (__attribute__((address_space(3))) unsigned int*)((char*)Bs + o), 16, 0, 0);
    }
    __syncthreads();
    #pragma unroll
    for (int kk = 0; kk < 2; kk++){
      const int kb = kk*32 + l4*8;
      bfx8 af[4], bf[NFB];
      #pragma unroll
      for (int mi = 0; mi < 4; mi++)
        af[mi] = *reinterpret_cast<const bfx8*>(&As[(wr*64 + mi*16 + l15)*64 + kb]);
      #pragma unroll
      for (int ni = 0; ni < NFB; ni++)
        bf[ni] = *reinterpret_cast<const bfx8*>(&Bs[(wc*(BN/2) + ni*16 + l15)*64 + kb]);
      #pragma unroll
      for (int mi = 0; mi < 4; mi++)
        #pragma unroll
        for (int ni = 0; ni < NFB; ni++)
          acc[mi][ni] = __builtin_amdgcn_mfma_f32_16x16x32_bf16(af[mi], bf[ni], acc[mi][ni], 0,0,0);
    }
  }

  const int rbase = m0 + wr*64 + l4*4;
  const int cbase = n0 + wc*(BN/2) + l15;
  #pragma unroll
  for (int mi = 0; mi < 4; mi++)
  #pragma unroll
  for (int ni = 0; ni < NFB; ni++){
    const int nn = cbase + ni*16;
    float bv = 0.f;
    if constexpr (HASBIAS) bv = bias[nn];
    #pragma unroll
    for (int r = 0; r < 4; r++){
      const int mm = rbase + mi*16 + r;
      float v = acc[mi][ni][r];
      if constexpr (HASBIAS) v += bv;
      if constexpr (RELU) v = fmaxf(v, 0.f);
      const long idx = (long)mm*ldc + nn;
      if constexpr (OUTF) Cf[idx] = v;
      if constexpr (OUTB) Cb[idx] = f2bf(v);
    }
  }
}

// ---------------- per-head V transpose: [B,Lk,E] pick head -> [B*H, 64, Lk] --------
__global__ __launch_bounds__(256) void transpose_v_kernel(const unsigned short* __restrict__ vp,
                                                          unsigned short* __restrict__ vt){
  __shared__ unsigned short T[128][66];
  const int z = blockIdx.x; const int b = z >> 4, h = z & 15;
  const int lk0 = blockIdx.y * 128;
  const int tid = threadIdx.x;
  #pragma unroll
  for (int c = 0; c < 4; c++){
    int ch = tid + c*256;
    int row = ch >> 3, col = (ch & 7) << 3;
    us8 v = *reinterpret_cast<const us8*>(vp + (long)b*LKV*E_DIM + (long)(lk0+row)*E_DIM + h*DHEAD + col);
    #pragma unroll
    for (int j = 0; j < 8; j++) T[row][col+j] = v[j];
  }
  __syncthreads();
  #pragma unroll
  for (int c = 0; c < 4; c++){
    int ch = tid + c*256;
    int d = ch >> 4, lkc = (ch & 15) << 3;
    us8 o;
    #pragma unroll
    for (int j = 0; j < 8; j++) o[j] = T[lkc+j][d];
    *reinterpret_cast<us8*>(vt + (long)z*DHEAD*LKV + (long)d*LKV + lk0 + lkc) = o;
  }
}

// ---------------- fused flash attention (two-pass, KV-split x4) --------------------
// grid 512 = 64 heads x 8 Q-tiles(64 rows). 16 waves: wave (wq,ws) = Q-strip wq (16
// rows) x KV-quarter ws (8 of 32 kt tiles). r7 lesson: occupancy/chain-length are NOT
// the limiter (205us invariant). r8: probs stores go wide — fp32 P-tile staged in LDS
// (Pf), written as 4x global_store_dwordx4 per wave per kt (1KB contiguous segments,
// memset-like) instead of 16 scalar 4B stores in the dependency window.
__global__ __launch_bounds__(1024) void attn_fused(
    const unsigned short* __restrict__ qp, const unsigned short* __restrict__ kp,
    const unsigned short* __restrict__ vt, float* __restrict__ probs,
    unsigned short* __restrict__ ctx)
{
  __shared__ unsigned short Pl[16][2][16][72];  // per-wave bf16 P-transpose, parity dbuf (73.7KB)
  __shared__ float Pf[16][16][68];              // per-wave fp32 P-tile for wide stores (69.6KB)
  __shared__ float MLm[16][16];
  __shared__ float MLl[16][16];
  float (*PVm)[16][64] = (float (*)[16][64])(void*)Pl;  // alias for PV merge (48KB)

  const int hw = blockIdx.x;
  const int logical = (hw & 7)*64 + (hw >> 3);   // XCD x gets heads 8x..8x+7 (K/V L2-resident)
  const int head = logical >> 3, qt = logical & 7;
  const int b = head >> 4, h = head & 15;

  const int tid = threadIdx.x, lane = tid & 63, w = tid >> 6;
  const int wq = w & 3, ws = w >> 2;
  const int l15 = lane & 15, l4 = lane >> 4;
  const int kt0 = ws*8, kt1 = kt0 + 8;
  const float SC = 0.18033688011112042f;         // 0.125 * log2(e)

  const unsigned short* qb = qp + ((long)(b*LQ + qt*64 + wq*16 + l15))*E_DIM + h*DHEAD + l4*8;
  bfx8 qf[2];
  qf[0] = *reinterpret_cast<const bfx8*>(qb);
  qf[1] = *reinterpret_cast<const bfx8*>(qb + 32);

  const unsigned short* kb = kp + ((long)(b*LKV) + l15)*E_DIM + h*DHEAD + l4*8;
  const unsigned short* vb = vt + ((long)head)*DHEAD*LKV + (long)l15*LKV + l4*8;

  float mloc[4] = {-1e30f,-1e30f,-1e30f,-1e30f};
  float psum[4] = {0.f,0.f,0.f,0.f};

  // ---- pass A: per-lane online (m, l) over this wave's KV quarter ----
  for (int kt = kt0; kt < kt1; kt++){
    f32x4 s[4] = {};
    #pragma unroll
    for (int kk = 0; kk < 2; kk++)
      #pragma unroll
      for (int nf = 0; nf < 4; nf++){
        bfx8 kf = *reinterpret_cast<const bfx8*>(kb + ((long)(kt*64 + nf*16))*E_DIM + kk*32);
        s[nf] = __builtin_amdgcn_mfma_f32_16x16x32_bf16(qf[kk], kf, s[nf], 0,0,0);
      }
    #pragma unroll
    for (int r = 0; r < 4; r++){
      float nm = mloc[r];
      float e0 = s[0][r]*SC, e1 = s[1][r]*SC, e2 = s[2][r]*SC, e3 = s[3][r]*SC;
      nm = fmaxf(nm, fmaxf(fmaxf(e0,e1), fmaxf(e2,e3)));
      float add = fexp2(e0-nm) + fexp2(e1-nm) + fexp2(e2-nm) + fexp2(e3-nm);
      psum[r] = psum[r]*fexp2(mloc[r]-nm) + add;
      mloc[r] = nm;
    }
  }
  #pragma unroll
  for (int r = 0; r < 4; r++){
    float m = mloc[r];
    m = fmaxf(m, __shfl_xor(m, 1)); m = fmaxf(m, __shfl_xor(m, 2));
    m = fmaxf(m, __shfl_xor(m, 4)); m = fmaxf(m, __shfl_xor(m, 8));
    float p = psum[r] * fexp2(mloc[r] - m);
    p += __shfl_xor(p, 1); p += __shfl_xor(p, 2);
    p += __shfl_xor(p, 4); p += __shfl_xor(p, 8);
    if (l15 == 0){ MLm[w][l4*4+r] = m; MLl[w][l4*4+r] = p; }
  }
  __syncthreads();
  float m2[4], linv[4];
  #pragma unroll
  for (int r = 0; r < 4; r++){
    const int row = l4*4 + r;
    float ma = MLm[wq   ][row], mb2 = MLm[wq+ 4][row];
    float mc = MLm[wq+ 8][row], md  = MLm[wq+12][row];
    float mg = fmaxf(fmaxf(ma,mb2), fmaxf(mc,md));
    float lg = MLl[wq   ][row]*fexp2(ma -mg) + MLl[wq+ 4][row]*fexp2(mb2-mg)
             + MLl[wq+ 8][row]*fexp2(mc -mg) + MLl[wq+12][row]*fexp2(md -mg);
    m2[r] = mg; linv[r] = 1.f / lg;
  }

  // ---- pass B: probs quarter (wide stores from Pf) + partial PV ----
  f32x4 pv[4] = {};
  // wide-store lane mapping: row = lane>>2 (of 16), 16-float chunk = lane&3
  float* pwide = probs + ((long)head*LQ + qt*64 + wq*16 + (lane>>2))*LKV + (lane&3)*16;
  const float4* pfsrc = reinterpret_cast<const float4*>(&Pf[w][lane>>2][(lane&3)*16]);
  for (int kt = kt0; kt < kt1; kt++){
    f32x4 s[4] = {};
    #pragma unroll
    for (int kk = 0; kk < 2; kk++)
      #pragma unroll
      for (int nf = 0; nf < 4; nf++){
        bfx8 kf = *reinterpret_cast<const bfx8*>(kb + ((long)(kt*64 + nf*16))*E_DIM + kk*32);
        s[nf] = __builtin_amdgcn_mfma_f32_16x16x32_bf16(qf[kk], kf, s[nf], 0,0,0);
      }
    const int par = kt & 1;
    #pragma unroll
    for (int nf = 0; nf < 4; nf++)
      #pragma unroll
      for (int r = 0; r < 4; r++){
        float pr = fexp2(s[nf][r]*SC - m2[r]) * linv[r];
        Pl[w][par][l4*4+r][nf*16+l15] = f2bf(pr);   // bf16 P for PV MFMA
        Pf[w][l4*4+r][nf*16+l15] = pr;              // fp32 P for wide probs store
      }
    #pragma unroll
    for (int kk = 0; kk < 2; kk++){
      bfx8 pa = *reinterpret_cast<const bfx8*>(&Pl[w][par][l15][kk*32 + l4*8]);
      #pragma unroll
      for (int nf = 0; nf < 4; nf++){
        bfx8 vf = *reinterpret_cast<const bfx8*>(vb + (long)(nf*16)*LKV + kt*64 + kk*32);
        pv[nf] = __builtin_amdgcn_mfma_f32_16x16x32_bf16(pa, vf, pv[nf], 0,0,0);
      }
    }
    // wide probs store: wave writes 16 rows x 256B (this kt's 64-col slab), 1KB/instr
    float* pd = pwide + kt*64;
    #pragma unroll
    for (int i = 0; i < 4; i++)
      *reinterpret_cast<float4*>(pd + i*4) = pfsrc[i];
  }

  // ---- merge partial PV across KV-quarters (PVm aliases Pl; all Pl reads done) ----
  __syncthreads();
  if (ws != 0){
    const int i = (ws-1)*4 + wq;
    #pragma unroll
    for (int nf = 0; nf < 4; nf++)
      #pragma unroll
      for (int r = 0; r < 4; r++)
        PVm[i][l4*4+r][nf*16+l15] = pv[nf][r];
  }
  __syncthreads();
  if (ws == 0){
    #pragma unroll
    for (int nf = 0; nf < 4; nf++)
      #pragma unroll
      for (int r = 0; r < 4; r++){
        float v = pv[nf][r];
        v += PVm[wq  ][l4*4+r][nf*16+l15];
        v += PVm[wq+4][l4*4+r][nf*16+l15];
        v += PVm[wq+8][l4*4+r][nf*16+l15];
        pv[nf][r] = v;
      }
    unsigned short* crow = ctx + ((long)(b*LQ + qt*64 + wq*16 + l4*4))*E_DIM + h*DHEAD + l15;
    #pragma unroll
    for (int nf = 0; nf < 4; nf++)
      #pragma unroll
      for (int r = 0; r < 4; r++)
        crow[(long)r*E_DIM + nf*16] = f2bf(pv[nf][r]);
  }
}

// ---------------- fused residual + LayerNorm over E=1024 ---------------------------
template<bool OUTB>
__global__ __launch_bounds__(256) void ln_kernel(
    const float* __restrict__ X, const float* __restrict__ Y,
    const float* __restrict__ g, const float* __restrict__ be,
    float* __restrict__ outF, unsigned short* __restrict__ outBp)
{
  __shared__ float redA[4], redB[4];
  const long base = (long)blockIdx.x * E_DIM;
  const int tid = threadIdx.x;
  float4 x = *reinterpret_cast<const float4*>(X + base + tid*4);
  float4 y = *reinterpret_cast<const float4*>(Y + base + tid*4);
  x.x += y.x; x.y += y.y; x.z += y.z; x.w += y.w;
  float s1 = x.x + x.y + x.z + x.w;
  float s2 = x.x*x.x + x.y*x.y + x.z*x.z + x.w*x.w;
  #pragma unroll
  for (int off = 32; off; off >>= 1){ s1 += __shfl_xor(s1, off); s2 += __shfl_xor(s2, off); }
  if ((tid & 63) == 0){ redA[tid>>6] = s1; redB[tid>>6] = s2; }
  __syncthreads();
  s1 = redA[0]+redA[1]+redA[2]+redA[3];
  s2 = redB[0]+redB[1]+redB[2]+redB[3];
  const float mean = s1 * (1.0f/E_DIM);
  const float var  = s2 * (1.0f/E_DIM) - mean*mean;
  const float inv  = rsqrtf(var + 1e-5f);
  float4 gv = *reinterpret_cast<const float4*>(g  + tid*4);
  float4 bv = *reinterpret_cast<const float4*>(be + tid*4);
  float4 o;
  o.x = (x.x - mean)*inv*gv.x + bv.x;
  o.y = (x.y - mean)*inv*gv.y + bv.y;
  o.z = (x.z - mean)*inv*gv.z + bv.z;
  o.w = (x.w - mean)*inv*gv.w + bv.w;
  *reinterpret_cast<float4*>(outF + base + tid*4) = o;
  if constexpr (OUTB){
    us4 ob; ob[0]=f2bf(o.x); ob[1]=f2bf(o.y); ob[2]=f2bf(o.z); ob[3]=f2bf(o.w);
    *reinterpret_cast<us4*>(outBp + base + tid*4) = ob;
  }
}

extern "C" void kernel_launch(void* const* d_in, const int* in_sizes, int n_in,
                              void* d_out, int out_size, void* d_ws, size_t ws_size,
                              hipStream_t stream)
{
  const float* query     = (const float*)d_in[0];
  const float* key_value = (const float*)d_in[1];
  const float* wq = (const float*)d_in[2];
  const float* wk = (const float*)d_in[3];
  const float* wv = (const float*)d_in[4];
  const float* bq = (const float*)d_in[5];
  const float* bk = (const float*)d_in[6];
  const float* bv = (const float*)d_in[7];
  const float* wo = (const float*)d_in[8];
  const float* bo = (const float*)d_in[9];
  const float* g1 = (const float*)d_in[10];
  const float* be1= (const float*)d_in[11];
  const float* w1 = (const float*)d_in[12];
  const float* b1 = (const float*)d_in[13];
  const float* w2 = (const float*)d_in[14];
  const float* b2 = (const float*)d_in[15];
  const float* g2 = (const float*)d_in[16];
  const float* be2= (const float*)d_in[17];

  float* q3   = (float*)d_out;                         // [4,512,1024]
  float* attn = q3 + (size_t)NB*LQ*E_DIM;              // [4,16,512,2048] probs (fp32)

  // workspace (aliased; liveness-disjoint)
  unsigned short* u = (unsigned short*)d_ws;
  unsigned short* xq_b  = u; u += 2097152;
  unsigned short* xkv_b = u; u += 8388608;
  unsigned short* wq_b  = u; u += 1048576;
  unsigned short* wk_b  = u; u += 1048576;
  unsigned short* wv_b  = u; u += 1048576;
  unsigned short* wo_b  = u; u += 1048576;
  unsigned short* w1_b  = u; u += 4194304;
  unsigned short* w2_b  = u; u += 4194304;
  unsigned short* qp_b  = u; u += 2097152;   // Q proj
  unsigned short* kp_b  = u; u += 8388608;   // K proj
  unsigned short* vp_b  = u; u += 8388608;   // V proj
  unsigned short* vt_b  = u; u += 8388608;   // V^T per head
  unsigned short* ctx_b = u; u += 2097152;   // attn ctx
  unsigned short* q2_b  = u; u += 2097152;   // LN1 out bf16
  float* attn_out_f = (float*)xkv_b;   // dead after V-proj
  float* q2_f       = (float*)kp_b;    // dead after attn_fused
  float* ffn_f      = (float*)vp_b;    // dead after transpose_v
  unsigned short* h1_b = vt_b;         // dead after attn_fused

  const dim3 blk(256);

  // 1. fp32 -> bf16
  cvt_kernel<<<dim3(1024), blk, 0, stream>>>(query, xq_b);
  cvt_kernel<<<dim3(4096), blk, 0, stream>>>(key_value, xkv_b);
  cvt_kernel<<<dim3(512),  blk, 0, stream>>>(wq, wq_b);
  cvt_kernel<<<dim3(512),  blk, 0, stream>>>(wk, wk_b);
  cvt_kernel<<<dim3(512),  blk, 0, stream>>>(wv, wv_b);
  cvt_kernel<<<dim3(512),  blk, 0, stream>>>(wo, wo_b);
  cvt_kernel<<<dim3(2048), blk, 0, stream>>>(w1, w1_b);
  cvt_kernel<<<dim3(2048), blk, 0, stream>>>(w2, w2_b);

  // 2. projections
  gemm128<64 ,true,false,false,true><<<dim3(16,16), blk, 0, stream>>>(
      xq_b, wq_b, bq, nullptr, qp_b, NB*LQ, E_DIM, E_DIM, E_DIM, E_DIM, E_DIM);
  gemm128<128,true,false,false,true><<<dim3(8,64), blk, 0, stream>>>(
      xkv_b, wk_b, bk, nullptr, kp_b, NB*LKV, E_DIM, E_DIM, E_DIM, E_DIM, E_DIM);
  gemm128<128,true,false,false,true><<<dim3(8,64), blk, 0, stream>>>(
      xkv_b, wv_b, bv, nullptr, vp_b, NB*LKV, E_DIM, E_DIM, E_DIM, E_DIM, E_DIM);

  // 3. V^T per head
  transpose_v_kernel<<<dim3(NB*NHEAD, LKV/128), blk, 0, stream>>>(vp_b, vt_b);

  // 4. fused attention: probs -> d_out (wide stores), ctx -> ctx_b
  attn_fused<<<dim3(512), dim3(1024), 0, stream>>>(qp_b, kp_b, vt_b, attn, ctx_b);

  // 5. attn_out = ctx @ wo^T + bo
  gemm128<64,true,false,true,false><<<dim3(16,16), blk, 0, stream>>>(
      ctx_b, wo_b, bo, attn_out_f, nullptr, NB*LQ, E_DIM, E_DIM, E_DIM, E_DIM, E_DIM);

  // 6. q2 = LN1(query + attn_out)
  ln_kernel<true><<<dim3(NB*LQ), blk, 0, stream>>>(query, attn_out_f, g1, be1, q2_f, q2_b);

  // 7. h1 = relu(q2 @ w1^T + b1)
  gemm128<128,true,true,false,true><<<dim3(32,16), blk, 0, stream>>>(
      q2_b, w1_b, b1, nullptr, h1_b, NB*LQ, FDIM, E_DIM, E_DIM, E_DIM, FDIM);

  // 8. ffn = h1 @ w2^T + b2
  gemm128<64,true,false,true,false><<<dim3(16,16), blk, 0, stream>>>(
      h1_b, w2_b, b2, ffn_f, nullptr, NB*LQ, E_DIM, FDIM, FDIM, FDIM, E_DIM);

  // 9. q3 = LN2(q2 + ffn) -> d_out
  ln_kernel<false><<<dim3(NB*LQ), blk, 0, stream>>>(q2_f, ffn_f, g2, be2, q3, nullptr);
}

// Round 9
// 678.994 us; speedup vs baseline: 1.1625x; 1.1625x over previous
//
#include <hip/hip_runtime.h>
#include <hip/hip_bf16.h>

#define E_DIM 1024
#define NHEAD 16
#define DHEAD 64
#define FDIM 4096
#define LQ 512
#define LKV 2048
#define NB 4

typedef __bf16 bfx8 __attribute__((ext_vector_type(8)));
typedef float f32x4 __attribute__((ext_vector_type(4)));
typedef unsigned short us8 __attribute__((ext_vector_type(8)));
typedef unsigned short us4 __attribute__((ext_vector_type(4)));

__device__ __forceinline__ unsigned short f2bf(float f){
  union { float f; unsigned int u; } v; v.f = f;
  unsigned int u = v.u;
  u += 0x7FFFu + ((u >> 16) & 1u);   // RNE
  return (unsigned short)(u >> 16);
}

__device__ __forceinline__ float fexp2(float x){
#if __has_builtin(__builtin_amdgcn_exp2f)
  return __builtin_amdgcn_exp2f(x);
#else
  return exp2f(x);
#endif
}

// ---------------- fp32 -> bf16 convert (8 elems/thread, exact grid) ----------------
__global__ __launch_bounds__(256) void cvt_kernel(const float* __restrict__ src,
                                                  unsigned short* __restrict__ dst){
  size_t i = ((size_t)blockIdx.x * 256 + threadIdx.x) * 8;
  float4 a = *reinterpret_cast<const float4*>(src + i);
  float4 b = *reinterpret_cast<const float4*>(src + i + 4);
  us8 o;
  o[0]=f2bf(a.x); o[1]=f2bf(a.y); o[2]=f2bf(a.z); o[3]=f2bf(a.w);
  o[4]=f2bf(b.x); o[5]=f2bf(b.y); o[6]=f2bf(b.z); o[7]=f2bf(b.w);
  *reinterpret_cast<us8*>(dst + i) = o;
}

// ---------------- m97-structure GEMM: 128xBN tile, BK=64, global_load_lds(16B) -----
template<int BN, bool HASBIAS, bool RELU, bool OUTF, bool OUTB>
__global__ __launch_bounds__(256) void gemm128(
    const unsigned short* __restrict__ A, const unsigned short* __restrict__ W,
    const float* __restrict__ bias, float* __restrict__ Cf, unsigned short* __restrict__ Cb,
    int M, int N, int K, int lda, int ldw, int ldc)
{
  constexpr int BM  = 128;
  constexpr int NFB = BN / 32;
  __shared__ unsigned short As[BM * 64];
  __shared__ unsigned short Bs[BN * 64];

  const int tid = threadIdx.x, lane = tid & 63, w = tid >> 6;
  const int wr = w >> 1, wc = w & 1;
  const int m0 = blockIdx.y * BM, n0 = blockIdx.x * BN;
  const int l15 = lane & 15, l4 = lane >> 4;

  f32x4 acc[4][NFB] = {};

  for (int k0 = 0; k0 < K; k0 += 64){
    __syncthreads();
    #pragma unroll
    for (int c = 0; c < BM/32; c++){
      const int o = (c*256 + tid) * 16;
      const int row = o >> 7, colb = o & 127;
      __builtin_amdgcn_global_load_lds(
        (const __attribute__((address_space(1))) void*)
            ((const char*)A + ((long)(m0+row)*lda + k0)*2 + colb),
        (__attribute__((address_space(3))) unsigned int*)((char*)As + o), 16, 0, 0);
    }
    #pragma unroll
    for (int c = 0; c < BN/32; c++){
      const int o = (c*256 + tid) * 16;
      const int row = o >> 7, colb = o & 127;
      __builtin_amdgcn_global_load_lds(
        (const __attribute__((address_space(1))) void*)
            ((const char*)W + ((long)(n0+row)*ldw + k0)*2 + colb),
        (__attribute__((address_space(3))) unsigned int*)((char*)Bs + o), 16, 0, 0);
    }
    __syncthreads();
    #pragma unroll
    for (int kk = 0; kk < 2; kk++){
      const int kb = kk*32 + l4*8;
      bfx8 af[4], bf[NFB];
      #pragma unroll
      for (int mi = 0; mi < 4; mi++)
        af[mi] = *reinterpret_cast<const bfx8*>(&As[(wr*64 + mi*16 + l15)*64 + kb]);
      #pragma unroll
      for (int ni = 0; ni < NFB; ni++)
        bf[ni] = *reinterpret_cast<const bfx8*>(&Bs[(wc*(BN/2) + ni*16 + l15)*64 + kb]);
      #pragma unroll
      for (int mi = 0; mi < 4; mi++)
        #pragma unroll
        for (int ni = 0; ni < NFB; ni++)
          acc[mi][ni] = __builtin_amdgcn_mfma_f32_16x16x32_bf16(af[mi], bf[ni], acc[mi][ni], 0,0,0);
    }
  }

  const int rbase = m0 + wr*64 + l4*4;
  const int cbase = n0 + wc*(BN/2) + l15;
  #pragma unroll
  for (int mi = 0; mi < 4; mi++)
  #pragma unroll
  for (int ni = 0; ni < NFB; ni++){
    const int nn = cbase + ni*16;
    float bv = 0.f;
    if constexpr (HASBIAS) bv = bias[nn];
    #pragma unroll
    for (int r = 0; r < 4; r++){
      const int mm = rbase + mi*16 + r;
      float v = acc[mi][ni][r];
      if constexpr (HASBIAS) v += bv;
      if constexpr (RELU) v = fmaxf(v, 0.f);
      const long idx = (long)mm*ldc + nn;
      if constexpr (OUTF) Cf[idx] = v;
      if constexpr (OUTB) Cb[idx] = f2bf(v);
    }
  }
}

// ---------------- per-head V transpose: [B,Lk,E] pick head -> [B*H, 64, Lk] --------
__global__ __launch_bounds__(256) void transpose_v_kernel(const unsigned short* __restrict__ vp,
                                                          unsigned short* __restrict__ vt){
  __shared__ unsigned short T[128][66];
  const int z = blockIdx.x; const int b = z >> 4, h = z & 15;
  const int lk0 = blockIdx.y * 128;
  const int tid = threadIdx.x;
  #pragma unroll
  for (int c = 0; c < 4; c++){
    int ch = tid + c*256;
    int row = ch >> 3, col = (ch & 7) << 3;
    us8 v = *reinterpret_cast<const us8*>(vp + (long)b*LKV*E_DIM + (long)(lk0+row)*E_DIM + h*DHEAD + col);
    #pragma unroll
    for (int j = 0; j < 8; j++) T[row][col+j] = v[j];
  }
  __syncthreads();
  #pragma unroll
  for (int c = 0; c < 4; c++){
    int ch = tid + c*256;
    int d = ch >> 4, lkc = (ch & 15) << 3;
    us8 o;
    #pragma unroll
    for (int j = 0; j < 8; j++) o[j] = T[lkc+j][d];
    *reinterpret_cast<us8*>(vt + (long)z*DHEAD*LKV + (long)d*LKV + lk0 + lkc) = o;
  }
}

// ---------------- fused flash attention (two-pass, LDS-staged K/V) -----------------
// grid 512 = 64 heads x 8 Q-tiles. 4 waves, wave w owns Q-rows w*16..+15, all waves
// sweep the same kt lockstep. K/V tiles staged to LDS via global_load_lds (double-
// buffered, issued 1 iter ahead; barrier-drain = ready). Fragments via ds_read_b128
// with XOR swizzle (row&7)<<4 applied to BOTH pre-swizzled global source and read
// address (rule 21). r6-r8 lesson: occupancy/chains/store-width all non-limiting;
// this attacks the 16-line-scatter + 4x-redundant global fragment loads.
__global__ __launch_bounds__(256) void attn_fused(
    const unsigned short* __restrict__ qp, const unsigned short* __restrict__ kp,
    const unsigned short* __restrict__ vt, float* __restrict__ probs,
    unsigned short* __restrict__ ctx)
{
  __shared__ unsigned short Ks[2][64*64];        // 16KB, [row][128B] swizzled
  __shared__ unsigned short Vs[2][64*64];        // 16KB, [d][128B] swizzled
  __shared__ unsigned short Pl[4][2][16][72];    // 18KB per-wave P-transpose

  const int hw = blockIdx.x;
  const int logical = (hw & 7)*64 + (hw >> 3);   // same head's q-tiles -> same XCD
  const int head = logical >> 3, qt = logical & 7;
  const int b = head >> 4, h = head & 15;

  const int tid = threadIdx.x, lane = tid & 63, w = tid >> 6;
  const int l15 = lane & 15, l4 = lane >> 4;
  const float SC = 0.18033688011112042f;         // 0.125 * log2(e)

  const unsigned short* qb = qp + ((long)(b*LQ + qt*64 + w*16 + l15))*E_DIM + h*DHEAD + l4*8;
  bfx8 qf[2];
  qf[0] = *reinterpret_cast<const bfx8*>(qb);
  qf[1] = *reinterpret_cast<const bfx8*>(qb + 32);

  const unsigned short* kbase = kp + (long)(b*LKV)*E_DIM + h*DHEAD;  // row stride E_DIM
  const unsigned short* vbase = vt + (long)head*DHEAD*LKV;           // row stride LKV

  // stage one 64x64 bf16 tile (8KB): 512 slots of 16B, 2 per thread; linear LDS dest,
  // inverse-swizzled global source (involution: same XOR on read side)
  auto stageK = [&](int kt, int buf){
    #pragma unroll
    for (int c = 0; c < 2; c++){
      const int s = c*256 + tid;
      const int row = s >> 3;
      const int colb = ((s & 7) << 4) ^ ((row & 7) << 4);
      __builtin_amdgcn_global_load_lds(
        (const __attribute__((address_space(1))) void*)
            ((const char*)(kbase + (long)(kt*64 + row)*E_DIM) + colb),
        (__attribute__((address_space(3))) unsigned int*)((char*)&Ks[buf][0] + s*16), 16, 0, 0);
    }
  };
  auto stageV = [&](int kt, int buf){
    #pragma unroll
    for (int c = 0; c < 2; c++){
      const int s = c*256 + tid;
      const int row = s >> 3;                    // d index
      const int colb = ((s & 7) << 4) ^ ((row & 7) << 4);
      __builtin_amdgcn_global_load_lds(
        (const __attribute__((address_space(1))) void*)
            ((const char*)(vbase + (long)row*LKV + kt*64) + colb),
        (__attribute__((address_space(3))) unsigned int*)((char*)&Vs[buf][0] + s*16), 16, 0, 0);
    }
  };
  // fragment read: row = nf*16+l15, col bytes = kk*64 + l4*16, same XOR
  auto fragLds = [&](const unsigned short* base, int nf, int kk) -> bfx8 {
    const int row = nf*16 + l15;
    const int colb = (kk*64 + l4*16) ^ ((row & 7) << 4);
    return *reinterpret_cast<const bfx8*>((const char*)base + row*128 + colb);
  };

  float mloc[4] = {-1e30f,-1e30f,-1e30f,-1e30f};
  float psum[4] = {0.f,0.f,0.f,0.f};

  // ---- pass A: online (m,l); K from LDS, staged 1 iter ahead ----
  stageK(0, 0);
  for (int kt = 0; kt < LKV/64; kt++){
    __syncthreads();                         // drains stage(kt) [compiler vmcnt(0)]
    if (kt < LKV/64 - 1) stageK(kt+1, (kt+1)&1);
    f32x4 s[4] = {};
    #pragma unroll
    for (int kk = 0; kk < 2; kk++)
      #pragma unroll
      for (int nf = 0; nf < 4; nf++)
        s[nf] = __builtin_amdgcn_mfma_f32_16x16x32_bf16(qf[kk], fragLds(&Ks[kt&1][0], nf, kk), s[nf], 0,0,0);
    #pragma unroll
    for (int r = 0; r < 4; r++){
      float nm = mloc[r];
      float e0 = s[0][r]*SC, e1 = s[1][r]*SC, e2 = s[2][r]*SC, e3 = s[3][r]*SC;
      nm = fmaxf(nm, fmaxf(fmaxf(e0,e1), fmaxf(e2,e3)));
      float add = fexp2(e0-nm) + fexp2(e1-nm) + fexp2(e2-nm) + fexp2(e3-nm);
      psum[r] = psum[r]*fexp2(mloc[r]-nm) + add;
      mloc[r] = nm;
    }
  }
  // merge across the 16-lane col groups (wave-private)
  float m2[4], linv[4];
  #pragma unroll
  for (int r = 0; r < 4; r++){
    float m = mloc[r];
    m = fmaxf(m, __shfl_xor(m, 1)); m = fmaxf(m, __shfl_xor(m, 2));
    m = fmaxf(m, __shfl_xor(m, 4)); m = fmaxf(m, __shfl_xor(m, 8));
    float p = psum[r] * fexp2(mloc[r] - m);
    p += __shfl_xor(p, 1); p += __shfl_xor(p, 2);
    p += __shfl_xor(p, 4); p += __shfl_xor(p, 8);
    m2[r] = m; linv[r] = 1.f / p;
  }

  // ---- pass B: probs write + PV; K,V from LDS ----
  f32x4 pv[4] = {};
  float* prow = probs + ((long)head*LQ + qt*64 + w*16 + l4*4)*LKV + l15;
  stageK(0, 0); stageV(0, 0);                // buf0 last read at kt=30 of pass A: safe
  for (int kt = 0; kt < LKV/64; kt++){
    __syncthreads();
    if (kt < LKV/64 - 1){ stageK(kt+1, (kt+1)&1); stageV(kt+1, (kt+1)&1); }
    f32x4 s[4] = {};
    #pragma unroll
    for (int kk = 0; kk < 2; kk++)
      #pragma unroll
      for (int nf = 0; nf < 4; nf++)
        s[nf] = __builtin_amdgcn_mfma_f32_16x16x32_bf16(qf[kk], fragLds(&Ks[kt&1][0], nf, kk), s[nf], 0,0,0);
    const int par = kt & 1;
    #pragma unroll
    for (int nf = 0; nf < 4; nf++)
      #pragma unroll
      for (int r = 0; r < 4; r++){
        float pr = fexp2(s[nf][r]*SC - m2[r]) * linv[r];
        prow[(long)r*LKV + kt*64 + nf*16] = pr;            // fp32 probs -> d_out
        Pl[w][par][l4*4+r][nf*16+l15] = f2bf(pr);          // bf16 P for PV
      }
    #pragma unroll
    for (int kk = 0; kk < 2; kk++){
      bfx8 pa = *reinterpret_cast<const bfx8*>(&Pl[w][par][l15][kk*32 + l4*8]);
      #pragma unroll
      for (int nf = 0; nf < 4; nf++)
        pv[nf] = __builtin_amdgcn_mfma_f32_16x16x32_bf16(pa, fragLds(&Vs[par][0], nf, kk), pv[nf], 0,0,0);
    }
  }
  // ctx write (bf16, interleaved [B,Lq,E])
  unsigned short* crow = ctx + ((long)(b*LQ + qt*64 + w*16 + l4*4))*E_DIM + h*DHEAD + l15;
  #pragma unroll
  for (int nf = 0; nf < 4; nf++)
    #pragma unroll
    for (int r = 0; r < 4; r++)
      crow[(long)r*E_DIM + nf*16] = f2bf(pv[nf][r]);
}

// ---------------- fused residual + LayerNorm over E=1024 ---------------------------
template<bool OUTB>
__global__ __launch_bounds__(256) void ln_kernel(
    const float* __restrict__ X, const float* __restrict__ Y,
    const float* __restrict__ g, const float* __restrict__ be,
    float* __restrict__ outF, unsigned short* __restrict__ outBp)
{
  __shared__ float redA[4], redB[4];
  const long base = (long)blockIdx.x * E_DIM;
  const int tid = threadIdx.x;
  float4 x = *reinterpret_cast<const float4*>(X + base + tid*4);
  float4 y = *reinterpret_cast<const float4*>(Y + base + tid*4);
  x.x += y.x; x.y += y.y; x.z += y.z; x.w += y.w;
  float s1 = x.x + x.y + x.z + x.w;
  float s2 = x.x*x.x + x.y*x.y + x.z*x.z + x.w*x.w;
  #pragma unroll
  for (int off = 32; off; off >>= 1){ s1 += __shfl_xor(s1, off); s2 += __shfl_xor(s2, off); }
  if ((tid & 63) == 0){ redA[tid>>6] = s1; redB[tid>>6] = s2; }
  __syncthreads();
  s1 = redA[0]+redA[1]+redA[2]+redA[3];
  s2 = redB[0]+redB[1]+redB[2]+redB[3];
  const float mean = s1 * (1.0f/E_DIM);
  const float var  = s2 * (1.0f/E_DIM) - mean*mean;
  const float inv  = rsqrtf(var + 1e-5f);
  float4 gv = *reinterpret_cast<const float4*>(g  + tid*4);
  float4 bv = *reinterpret_cast<const float4*>(be + tid*4);
  float4 o;
  o.x = (x.x - mean)*inv*gv.x + bv.x;
  o.y = (x.y - mean)*inv*gv.y + bv.y;
  o.z = (x.z - mean)*inv*gv.z + bv.z;
  o.w = (x.w - mean)*inv*gv.w + bv.w;
  *reinterpret_cast<float4*>(outF + base + tid*4) = o;
  if constexpr (OUTB){
    us4 ob; ob[0]=f2bf(o.x); ob[1]=f2bf(o.y); ob[2]=f2bf(o.z); ob[3]=f2bf(o.w);
    *reinterpret_cast<us4*>(outBp + base + tid*4) = ob;
  }
}

extern "C" void kernel_launch(void* const* d_in, const int* in_sizes, int n_in,
                              void* d_out, int out_size, void* d_ws, size_t ws_size,
                              hipStream_t stream)
{
  const float* query     = (const float*)d_in[0];
  const float* key_value = (const float*)d_in[1];
  const float* wq = (const float*)d_in[2];
  const float* wk = (const float*)d_in[3];
  const float* wv = (const float*)d_in[4];
  const float* bq = (const float*)d_in[5];
  const float* bk = (const float*)d_in[6];
  const float* bv = (const float*)d_in[7];
  const float* wo = (const float*)d_in[8];
  const float* bo = (const float*)d_in[9];
  const float* g1 = (const float*)d_in[10];
  const float* be1= (const float*)d_in[11];
  const float* w1 = (const float*)d_in[12];
  const float* b1 = (const float*)d_in[13];
  const float* w2 = (const float*)d_in[14];
  const float* b2 = (const float*)d_in[15];
  const float* g2 = (const float*)d_in[16];
  const float* be2= (const float*)d_in[17];

  float* q3   = (float*)d_out;                         // [4,512,1024]
  float* attn = q3 + (size_t)NB*LQ*E_DIM;              // [4,16,512,2048] probs (fp32)

  // workspace (aliased; liveness-disjoint)
  unsigned short* u = (unsigned short*)d_ws;
  unsigned short* xq_b  = u; u += 2097152;
  unsigned short* xkv_b = u; u += 8388608;
  unsigned short* wq_b  = u; u += 1048576;
  unsigned short* wk_b  = u; u += 1048576;
  unsigned short* wv_b  = u; u += 1048576;
  unsigned short* wo_b  = u; u += 1048576;
  unsigned short* w1_b  = u; u += 4194304;
  unsigned short* w2_b  = u; u += 4194304;
  unsigned short* qp_b  = u; u += 2097152;   // Q proj
  unsigned short* kp_b  = u; u += 8388608;   // K proj
  unsigned short* vp_b  = u; u += 8388608;   // V proj
  unsigned short* vt_b  = u; u += 8388608;   // V^T per head
  unsigned short* ctx_b = u; u += 2097152;   // attn ctx
  unsigned short* q2_b  = u; u += 2097152;   // LN1 out bf16
  float* attn_out_f = (float*)xkv_b;   // dead after V-proj
  float* q2_f       = (float*)kp_b;    // dead after attn_fused
  float* ffn_f      = (float*)vp_b;    // dead after transpose_v
  unsigned short* h1_b = vt_b;         // dead after attn_fused

  const dim3 blk(256);

  // 1. fp32 -> bf16
  cvt_kernel<<<dim3(1024), blk, 0, stream>>>(query, xq_b);
  cvt_kernel<<<dim3(4096), blk, 0, stream>>>(key_value, xkv_b);
  cvt_kernel<<<dim3(512),  blk, 0, stream>>>(wq, wq_b);
  cvt_kernel<<<dim3(512),  blk, 0, stream>>>(wk, wk_b);
  cvt_kernel<<<dim3(512),  blk, 0, stream>>>(wv, wv_b);
  cvt_kernel<<<dim3(512),  blk, 0, stream>>>(wo, wo_b);
  cvt_kernel<<<dim3(2048), blk, 0, stream>>>(w1, w1_b);
  cvt_kernel<<<dim3(2048), blk, 0, stream>>>(w2, w2_b);

  // 2. projections
  gemm128<64 ,true,false,false,true><<<dim3(16,16), blk, 0, stream>>>(
      xq_b, wq_b, bq, nullptr, qp_b, NB*LQ, E_DIM, E_DIM, E_DIM, E_DIM, E_DIM);
  gemm128<128,true,false,false,true><<<dim3(8,64), blk, 0, stream>>>(
      xkv_b, wk_b, bk, nullptr, kp_b, NB*LKV, E_DIM, E_DIM, E_DIM, E_DIM, E_DIM);
  gemm128<128,true,false,false,true><<<dim3(8,64), blk, 0, stream>>>(
      xkv_b, wv_b, bv, nullptr, vp_b, NB*LKV, E_DIM, E_DIM, E_DIM, E_DIM, E_DIM);

  // 3. V^T per head
  transpose_v_kernel<<<dim3(NB*NHEAD, LKV/128), blk, 0, stream>>>(vp_b, vt_b);

  // 4. fused attention (LDS-staged K/V): probs -> d_out, ctx -> ctx_b
  attn_fused<<<dim3(512), blk, 0, stream>>>(qp_b, kp_b, vt_b, attn, ctx_b);

  // 5. attn_out = ctx @ wo^T + bo
  gemm128<64,true,false,true,false><<<dim3(16,16), blk, 0, stream>>>(
      ctx_b, wo_b, bo, attn_out_f, nullptr, NB*LQ, E_DIM, E_DIM, E_DIM, E_DIM, E_DIM);

  // 6. q2 = LN1(query + attn_out)
  ln_kernel<true><<<dim3(NB*LQ), blk, 0, stream>>>(query, attn_out_f, g1, be1, q2_f, q2_b);

  // 7. h1 = relu(q2 @ w1^T + b1)
  gemm128<128,true,true,false,true><<<dim3(32,16), blk, 0, stream>>>(
      q2_b, w1_b, b1, nullptr, h1_b, NB*LQ, FDIM, E_DIM, E_DIM, E_DIM, FDIM);

  // 8. ffn = h1 @ w2^T + b2
  gemm128<64,true,false,true,false><<<dim3(16,16), blk, 0, stream>>>(
      h1_b, w2_b, b2, ffn_f, nullptr, NB*LQ, E_DIM, FDIM, FDIM, FDIM, E_DIM);

  // 9. q3 = LN2(q2 + ffn) -> d_out
  ln_kernel<false><<<dim3(NB*LQ), blk, 0, stream>>>(q2_f, ffn_f, g2, be2, q3, nullptr);
}